// Round 5
// baseline (70.782 us; speedup 1.0000x reference)
//
#include <hip/hip_runtime.h>

// B=2048, L=128, V=30522, D=768. Masked-mean pooling over ragged prefixes.
// Persistent work-queue version: 1536 blocks (6/CU), each grabs full rows
// from a global atomic counter (first row = blockIdx.x, free). Fixes the
// ragged-drain imbalance (R4: OccupancyPercent 41% vs 75% static; CU time
// ~ E[max of 8 U(1,128)] = 114 vs mean 64.5 tokens). Row arithmetic order
// is fixed -> output deterministic despite dynamic assignment.
#define BB 2048
#define LL 128
#define DD 768
#define NT 192
#define DV (DD / 4)
#define GRID 1536

__device__ __forceinline__ void f4acc(float4& a, const float4 v) {
    a.x += v.x; a.y += v.y; a.z += v.z; a.w += v.w;
}

__global__ __launch_bounds__(NT) void pool_queue_kernel(
    const int* __restrict__ ids,      // [B, L] int32
    const int* __restrict__ mask,     // [B, L] int32 (0/1, left-contiguous)
    const float* __restrict__ emb,    // [V, D] fp32
    float* __restrict__ out,          // [B, D] fp32
    int* __restrict__ ctr)            // work-queue counter (zeroed per launch)
{
    const int t = threadIdx.x;

    __shared__ int s_ids[LL];
    __shared__ int s_part[2];
    __shared__ int s_next;

    const float4* __restrict__ embv = reinterpret_cast<const float4*>(emb);

    int b = blockIdx.x;               // first row: free, no atomic

    while (b < BB) {
        // ---- stage ids, count valid tokens (mask 0/1 left-contiguous) ----
        if (t < LL) {
            s_ids[t] = ids[b * LL + t];
            int m = mask[b * LL + t];
            unsigned long long bal = __ballot(m != 0);
            if ((t & 63) == 0) s_part[t >> 6] = __popcll(bal);
        }
        __syncthreads();
        const int cnt = s_part[0] + s_part[1];   // >= 1

        // ---- gather + accumulate (R4 pipelined body) ----
        float4 a0 = {0,0,0,0}, a1 = {0,0,0,0}, a2 = {0,0,0,0}, a3 = {0,0,0,0};

        int l = 0;
        if (cnt >= 8) {
            float4 r0 = embv[s_ids[0] * DV + t];
            float4 r1 = embv[s_ids[1] * DV + t];
            float4 r2 = embv[s_ids[2] * DV + t];
            float4 r3 = embv[s_ids[3] * DV + t];
            float4 r4 = embv[s_ids[4] * DV + t];
            float4 r5 = embv[s_ids[5] * DV + t];
            float4 r6 = embv[s_ids[6] * DV + t];
            float4 r7 = embv[s_ids[7] * DV + t];

            for (l = 8; l + 8 <= cnt; l += 8) {
                const int i0 = s_ids[l + 0], i1 = s_ids[l + 1];
                const int i2 = s_ids[l + 2], i3 = s_ids[l + 3];
                const int i4 = s_ids[l + 4], i5 = s_ids[l + 5];
                const int i6 = s_ids[l + 6], i7 = s_ids[l + 7];
                f4acc(a0, r0); r0 = embv[i0 * DV + t];
                f4acc(a1, r1); r1 = embv[i1 * DV + t];
                f4acc(a2, r2); r2 = embv[i2 * DV + t];
                f4acc(a3, r3); r3 = embv[i3 * DV + t];
                f4acc(a0, r4); r4 = embv[i4 * DV + t];
                f4acc(a1, r5); r5 = embv[i5 * DV + t];
                f4acc(a2, r6); r6 = embv[i6 * DV + t];
                f4acc(a3, r7); r7 = embv[i7 * DV + t];
            }
            f4acc(a0, r0); f4acc(a1, r1); f4acc(a2, r2); f4acc(a3, r3);
            f4acc(a0, r4); f4acc(a1, r5); f4acc(a2, r6); f4acc(a3, r7);
        }
        for (; l < cnt; ++l) {
            f4acc(a0, embv[s_ids[l] * DV + t]);
        }

        f4acc(a0, a2); f4acc(a1, a3);
        f4acc(a0, a1);

        const float inv = 1.0f / (float)cnt;
        float4 o;
        o.x = a0.x * inv; o.y = a0.y * inv; o.z = a0.z * inv; o.w = a0.w * inv;
        reinterpret_cast<float4*>(out)[b * DV + t] = o;

        // ---- grab next row ----
        __syncthreads();                      // s_ids/s_part reads done
        if (t == 0) s_next = GRID + atomicAdd(ctr, 1);
        __syncthreads();
        b = s_next;                           // block-uniform
    }
}

extern "C" void kernel_launch(void* const* d_in, const int* in_sizes, int n_in,
                              void* d_out, int out_size, void* d_ws, size_t ws_size,
                              hipStream_t stream) {
    const int*   ids  = (const int*)d_in[0];
    const int*   mask = (const int*)d_in[1];
    const float* emb  = (const float*)d_in[2];
    float*       out  = (float*)d_out;
    int*         ctr  = (int*)d_ws;

    hipMemsetAsync(ctr, 0, sizeof(int), stream);   // graph-capture safe
    pool_queue_kernel<<<GRID, NT, 0, stream>>>(ids, mask, emb, out, ctr);
}